// Round 7
// baseline (631.389 us; speedup 1.0000x reference)
//
#include <hip/hip_runtime.h>

#define NTOT 262144
#define BN   32
#define NT   256
#define SXS  296     // sX row stride in shorts (288 + 8 pad; conflict-free b128 reads)

typedef __attribute__((ext_vector_type(8))) short bf16x8;
typedef __attribute__((ext_vector_type(4))) float f32x4;

static __device__ __forceinline__ unsigned short f2b(float x) {
    union { float f; unsigned u; } c; c.f = x;
    unsigned r = c.u + 0x7FFFu + ((c.u >> 16) & 1u);   // RNE
    return (unsigned short)(r >> 16);
}
static __device__ __forceinline__ float b2f(unsigned short h) {
    union { unsigned u; float f; } c; c.u = ((unsigned)h) << 16; return c.f;
}
static __device__ __forceinline__ bf16x8 cvt8(const float* p) {
    float4 x = *(const float4*)p, y = *(const float4*)(p + 4);
    bf16x8 r;
    r[0] = (short)f2b(x.x); r[1] = (short)f2b(x.y); r[2] = (short)f2b(x.z); r[3] = (short)f2b(x.w);
    r[4] = (short)f2b(y.x); r[5] = (short)f2b(y.y); r[6] = (short)f2b(y.z); r[7] = (short)f2b(y.w);
    return r;
}
static __device__ __forceinline__ void glds16(const unsigned short* g, void* l) {
    __builtin_amdgcn_global_load_lds(
        (const __attribute__((address_space(1))) void*)g,
        (__attribute__((address_space(3))) void*)l, 16, 0, 0);
}

// Pack W_m_w -> bf16 in 18 half-chunks of [128 cols][32 k] (it = ks*2+ch), linear
// so each wave's glds slice (1024 shorts) is contiguous. W_g_w -> bf16 k-chunked.
__global__ void pack_w(const float* __restrict__ Wmw, const float* __restrict__ Wgw,
                       unsigned short* __restrict__ wp) {
    int t = blockIdx.x * 256 + threadIdx.x;
    if (t < 73728) {
        int o = t / 288, k = t % 288;
        int ks = k >> 5, kk = k & 31, ch = o >> 7, ol = o & 127;
        wp[(ks * 2 + ch) * 4096 + ol * 32 + kk] = f2b(Wmw[t]);
    } else if (t < 81920) {
        int j = t - 73728;
        int o = j >> 8, k = j & 255;
        wp[73728 + (k >> 5) * 1024 + o * 32 + (k & 31)] = f2b(Wgw[j]);
    }
}

// launch_bounds(NT,3): target 3 blocks/CU (reg cap ~170 -> no spill for ~110-reg
// live set). LDS 47,616 B -> 3 blocks/CU.
template<int USE_WS>
__global__ __launch_bounds__(NT, 3)
void gvp_main(const float* __restrict__ s, const float* __restrict__ V,
              const float* __restrict__ Wh, const float* __restrict__ Wmu,
              const float* __restrict__ Wmw, const float* __restrict__ Wmb,
              const float* __restrict__ Wgw, const float* __restrict__ Wgb,
              const unsigned short* __restrict__ wpack,
              float* __restrict__ out)
{
    // sX  bf16 [32][296] 18944 B: s cols 0-255 | s_h cols 256-287;
    //     after GEMM: sigmoid(s_m) cols 0-255, gate bf16 cols 256-287.
    // sWb      2 x 4096 shorts 16384 B: W half-chunk double buffer;
    //     after GEMM: f32 V_dash scratch [32][96] (12288 B).
    // sV  f32  [32][96]  12288 B: V tile, then V_h.
    __shared__ __attribute__((aligned(16))) unsigned short sX[BN * SXS];
    __shared__ __attribute__((aligned(16))) unsigned short sWb[2 * 4096];
    __shared__ __attribute__((aligned(16))) float sV[BN * 96];

    const int t  = threadIdx.x;
    const int w  = t >> 6, l = t & 63;
    const int fr = l & 15, fq = l >> 4;
    const int n0 = blockIdx.x * BN;

    // ---------------- stage s -> sX (bf16), V -> sV ----------------
    #pragma unroll
    for (int i = 0; i < 8; ++i) {
        int n = i * 4 + w;
        float4 x4 = *(const float4*)&s[(size_t)(n0 + n) * 256 + 4 * l];
        ushort4 h4; h4.x = f2b(x4.x); h4.y = f2b(x4.y); h4.z = f2b(x4.z); h4.w = f2b(x4.w);
        *(ushort4*)&sX[n * SXS + 4 * l] = h4;
    }
    #pragma unroll
    for (int i = 0; i < 3; ++i) {
        int f = i * NT + t;
        *(float4*)&sV[f * 4] = *(const float4*)&V[(size_t)n0 * 96 + f * 4];
    }
    // prologue: stage W half-chunk 0 into buf0 (wave-linear slice, async)
    if (USE_WS) {
        const unsigned short* src = wpack + w * 1024 + l * 8;
        unsigned short* dst = sWb + w * 1024;
        glds16(src, dst);
        glds16(src + 512, dst + 512);
    } else {
        int og = t >> 1, kh = t & 1;                 // ch=0, ks=0
        const float* p = &Wmw[og * 288 + kh * 16];
        *(bf16x8*)&sWb[og * 32 + kh * 16 + 0] = cvt8(p);
        *(bf16x8*)&sWb[og * 32 + kh * 16 + 8] = cvt8(p + 8);
    }
    __syncthreads();   // drains vmcnt -> chunk 0 resident; staging visible

    // ---------------- phase A: V_h = Wh@V (f32, Wh from L1), s_h -> sX[.,256..] --
    float vh[4][3];
    #pragma unroll
    for (int i = 0; i < 4; ++i) {
        int p = i * NT + t;
        int n = p >> 5, h = p & 31;
        const float4* vt4 = (const float4*)&sV[n * 96];
        const float4* wh4 = (const float4*)&Wh[h * 32];
        float a0 = 0.f, a1 = 0.f, a2 = 0.f;
        #pragma unroll
        for (int v4 = 0; v4 < 8; ++v4) {
            float4 wv = wh4[v4];
            float4 p0 = vt4[v4 * 3 + 0], p1 = vt4[v4 * 3 + 1], p2 = vt4[v4 * 3 + 2];
            a0 = fmaf(wv.x, p0.x, a0); a1 = fmaf(wv.x, p0.y, a1); a2 = fmaf(wv.x, p0.z, a2);
            a0 = fmaf(wv.y, p0.w, a0); a1 = fmaf(wv.y, p1.x, a1); a2 = fmaf(wv.y, p1.y, a2);
            a0 = fmaf(wv.z, p1.z, a0); a1 = fmaf(wv.z, p1.w, a1); a2 = fmaf(wv.z, p2.x, a2);
            a0 = fmaf(wv.w, p2.y, a0); a1 = fmaf(wv.w, p2.z, a1); a2 = fmaf(wv.w, p2.w, a2);
        }
        vh[i][0] = a0; vh[i][1] = a1; vh[i][2] = a2;
        float nrm = sqrtf(fmaf(a0, a0, fmaf(a1, a1, a2 * a2)));
        sX[n * SXS + 256 + h] = f2b(fmaxf(nrm, 1e-4f));
    }
    __syncthreads();            // V-tile reads done; s_h visible
    #pragma unroll
    for (int i = 0; i < 4; ++i) {
        int p = i * NT + t;
        int n = p >> 5, h = p & 31;
        sV[n * 96 + h * 3 + 0] = vh[i][0];
        sV[n * 96 + h * 3 + 1] = vh[i][1];
        sV[n * 96 + h * 3 + 2] = vh[i][2];
    }

    // ---------------- main GEMM: 18 half-chunk iters, dbuf glds, 1 barrier/iter --
    // acc[mt][ji]: ji = ch*2 + jt -> col = ch*128 + w*32 + jt*16 + fr
    f32x4 acc[2][4];
    #pragma unroll
    for (int mt = 0; mt < 2; ++mt)
        #pragma unroll
        for (int j = 0; j < 4; ++j) acc[mt][j] = (f32x4){0.f, 0.f, 0.f, 0.f};

    #pragma unroll
    for (int it = 0; it < 18; ++it) {
        if (it < 17) {          // stage next half-chunk into the other buffer
            if (USE_WS) {
                const unsigned short* src = wpack + (it + 1) * 4096 + w * 1024 + l * 8;
                unsigned short* dst = sWb + ((it + 1) & 1) * 4096 + w * 1024;
                glds16(src, dst);
                glds16(src + 512, dst + 512);
            } else {
                int ks1 = (it + 1) >> 1, ch1 = (it + 1) & 1;
                int og = ch1 * 128 + (t >> 1), kh = t & 1;
                const float* p = &Wmw[og * 288 + ks1 * 32 + kh * 16];
                *(bf16x8*)&sWb[((it + 1) & 1) * 4096 + (t >> 1) * 32 + kh * 16 + 0] = cvt8(p);
                *(bf16x8*)&sWb[((it + 1) & 1) * 4096 + (t >> 1) * 32 + kh * 16 + 8] = cvt8(p + 8);
            }
        }
        const int ks = it >> 1;
        const unsigned short* bw = sWb + (it & 1) * 4096;
        bf16x8 a0 = *(const bf16x8*)&sX[fr * SXS + ks * 32 + fq * 8];
        bf16x8 a1 = *(const bf16x8*)&sX[(16 + fr) * SXS + ks * 32 + fq * 8];
        bf16x8 b0 = *(const bf16x8*)&bw[(w * 32 + fr) * 32 + fq * 8];
        bf16x8 b1 = *(const bf16x8*)&bw[(w * 32 + 16 + fr) * 32 + fq * 8];
        const int ji = (it & 1) * 2;   // static under full unroll
        acc[0][ji + 0] = __builtin_amdgcn_mfma_f32_16x16x32_bf16(a0, b0, acc[0][ji + 0], 0, 0, 0);
        acc[1][ji + 0] = __builtin_amdgcn_mfma_f32_16x16x32_bf16(a1, b0, acc[1][ji + 0], 0, 0, 0);
        acc[0][ji + 1] = __builtin_amdgcn_mfma_f32_16x16x32_bf16(a0, b1, acc[0][ji + 1], 0, 0, 0);
        acc[1][ji + 1] = __builtin_amdgcn_mfma_f32_16x16x32_bf16(a1, b1, acc[1][ji + 1], 0, 0, 0);
        __syncthreads();        // buffer swap; drains glds for it+1
    }

    // ---------------- epilogue: relu -> out (direct), sigmoid -> sX cols 0-255 --
    float bias[4];
    #pragma unroll
    for (int ji = 0; ji < 4; ++ji)
        bias[ji] = Wmb[(ji >> 1) * 128 + w * 32 + (ji & 1) * 16 + fr];
    #pragma unroll
    for (int mt = 0; mt < 2; ++mt)
        #pragma unroll
        for (int r = 0; r < 4; ++r) {
            int node = mt * 16 + fq * 4 + r;
            #pragma unroll
            for (int ji = 0; ji < 4; ++ji) {
                int col = (ji >> 1) * 128 + w * 32 + (ji & 1) * 16 + fr;
                float m = acc[mt][ji][r] + bias[ji];
                out[(size_t)(n0 + node) * 256 + col] = fmaxf(m, 0.f);
                sX[node * SXS + col] = f2b(1.f / (1.f + __expf(-m)));
            }
        }
    __syncthreads();

    // ---------------- gate GEMM (B direct from global); gate bf16 -> sX[.,256..] -
    {
        const int gmt = w & 1, gnt = w >> 1;
        f32x4 g = (f32x4){0.f, 0.f, 0.f, 0.f};
        #pragma unroll
        for (int ks = 0; ks < 8; ++ks) {
            bf16x8 a = *(const bf16x8*)&sX[(gmt * 16 + fr) * SXS + ks * 32 + fq * 8];
            bf16x8 b;
            if (USE_WS) b = *(const bf16x8*)&wpack[73728 + ks * 1024 + (gnt * 16 + fr) * 32 + fq * 8];
            else        b = cvt8(&Wgw[(gnt * 16 + fr) * 256 + ks * 32 + fq * 8]);
            g = __builtin_amdgcn_mfma_f32_16x16x32_bf16(a, b, g, 0, 0, 0);
        }
        int mo = gnt * 16 + fr;
        float gb = Wgb[mo];
        #pragma unroll
        for (int r = 0; r < 4; ++r) {
            int node = gmt * 16 + fq * 4 + r;
            sX[node * SXS + 256 + mo] = f2b(1.f / (1.f + __expf(-(g[r] + gb))));
        }
    }
    __syncthreads();            // gate visible; sWb dead -> f32 V_dash scratch

    // ---------------- phase D: V_mu = Wmu@V_h (f32); gate; coalesced store ------
    float* sc = (float*)sWb;    // [32][96] f32 = 12288 B <= 16384 B
    #pragma unroll
    for (int i = 0; i < 4; ++i) {
        int p = i * NT + t;
        int n = p >> 5, m = p & 31;
        const float4* vt4 = (const float4*)&sV[n * 96];
        const float4* wm4 = (const float4*)&Wmu[m * 32];
        float a0 = 0.f, a1 = 0.f, a2 = 0.f;
        #pragma unroll
        for (int v4 = 0; v4 < 8; ++v4) {
            float4 wv = wm4[v4];
            float4 p0 = vt4[v4 * 3 + 0], p1 = vt4[v4 * 3 + 1], p2 = vt4[v4 * 3 + 2];
            a0 = fmaf(wv.x, p0.x, a0); a1 = fmaf(wv.x, p0.y, a1); a2 = fmaf(wv.x, p0.z, a2);
            a0 = fmaf(wv.y, p0.w, a0); a1 = fmaf(wv.y, p1.x, a1); a2 = fmaf(wv.y, p1.y, a2);
            a0 = fmaf(wv.z, p1.z, a0); a1 = fmaf(wv.z, p1.w, a1); a2 = fmaf(wv.z, p2.x, a2);
            a0 = fmaf(wv.w, p2.y, a0); a1 = fmaf(wv.w, p2.z, a1); a2 = fmaf(wv.w, p2.w, a2);
        }
        float g = b2f(sX[n * SXS + 256 + m]);
        sc[n * 96 + m * 3 + 0] = g * a0;
        sc[n * 96 + m * 3 + 1] = g * a1;
        sc[n * 96 + m * 3 + 2] = g * a2;
    }
    __syncthreads();
    const size_t VBASE = (size_t)NTOT * 256;
    #pragma unroll
    for (int i = 0; i < 3; ++i) {
        int f = i * NT + t;
        *(float4*)&out[VBASE + (size_t)n0 * 96 + f * 4] = *(const float4*)&sc[f * 4];
    }
}

extern "C" void kernel_launch(void* const* d_in, const int* in_sizes, int n_in,
                              void* d_out, int out_size, void* d_ws, size_t ws_size,
                              hipStream_t stream) {
    const float* s   = (const float*)d_in[0];
    const float* V   = (const float*)d_in[1];
    const float* Wh  = (const float*)d_in[2];
    const float* Wmu = (const float*)d_in[3];
    const float* Wmw = (const float*)d_in[4];
    const float* Wmb = (const float*)d_in[5];
    const float* Wgw = (const float*)d_in[6];
    const float* Wgb = (const float*)d_in[7];
    float* out = (float*)d_out;

    dim3 grid(NTOT / BN);   // 8192
    dim3 block(NT);         // 256

    if (ws_size >= 163840) {
        pack_w<<<320, 256, 0, stream>>>(Wmw, Wgw, (unsigned short*)d_ws);
        gvp_main<1><<<grid, block, 0, stream>>>(s, V, Wh, Wmu, Wmw, Wmb, Wgw, Wgb,
                                                (const unsigned short*)d_ws, out);
    } else {
        gvp_main<0><<<grid, block, 0, stream>>>(s, V, Wh, Wmu, Wmw, Wmb, Wgw, Wgb,
                                                nullptr, out);
    }
}

// Round 8
// 516.059 us; speedup vs baseline: 1.2235x; 1.2235x over previous
//
#include <hip/hip_runtime.h>

#define NTOT 262144
#define BN   32
#define NT   256
#define SXS  296     // sX row stride in shorts (288 + 8 pad; conflict-free b128 reads)

typedef __attribute__((ext_vector_type(8))) short bf16x8;
typedef __attribute__((ext_vector_type(4))) float f32x4;

static __device__ __forceinline__ unsigned short f2b(float x) {
    union { float f; unsigned u; } c; c.f = x;
    unsigned r = c.u + 0x7FFFu + ((c.u >> 16) & 1u);   // RNE
    return (unsigned short)(r >> 16);
}
static __device__ __forceinline__ float b2f(unsigned short h) {
    union { unsigned u; float f; } c; c.u = ((unsigned)h) << 16; return c.f;
}
static __device__ __forceinline__ bf16x8 cvt8(const float* p) {
    float4 x = *(const float4*)p, y = *(const float4*)(p + 4);
    bf16x8 r;
    r[0] = (short)f2b(x.x); r[1] = (short)f2b(x.y); r[2] = (short)f2b(x.z); r[3] = (short)f2b(x.w);
    r[4] = (short)f2b(y.x); r[5] = (short)f2b(y.y); r[6] = (short)f2b(y.z); r[7] = (short)f2b(y.w);
    return r;
}
static __device__ __forceinline__ void glds16(const unsigned short* g, void* l) {
    __builtin_amdgcn_global_load_lds(
        (const __attribute__((address_space(1))) void*)g,
        (__attribute__((address_space(3))) void*)l, 16, 0, 0);
}

// Pack W_m_w -> bf16 in 18 half-chunks of [128 cols][32 k] (it = ks*2+ch), linear
// so each wave's glds slice (1024 shorts) is contiguous. W_g_w -> bf16 k-chunked.
__global__ void pack_w(const float* __restrict__ Wmw, const float* __restrict__ Wgw,
                       unsigned short* __restrict__ wp) {
    int t = blockIdx.x * 256 + threadIdx.x;
    if (t < 73728) {
        int o = t / 288, k = t % 288;
        int ks = k >> 5, kk = k & 31, ch = o >> 7, ol = o & 127;
        wp[(ks * 2 + ch) * 4096 + ol * 32 + kk] = f2b(Wmw[t]);
    } else if (t < 81920) {
        int j = t - 73728;
        int o = j >> 8, k = j & 255;
        wp[73728 + (k >> 5) * 1024 + o * 32 + (k & 31)] = f2b(Wgw[j]);
    }
}

// launch_bounds(NT,2): proven no-spill regime (r2/r6 -> ~88 VGPR). Residency is
// set by LDS: 47,616 B -> 3 blocks/CU.
// ALL out-writes complete full cache lines in a single wave instruction
// (LDS-restaged f4 stores): at 3 blocks/CU, per-fragment direct stores left a
// 2-instruction completion window per 128B line; L2 pressure evicted half-dirty
// lines -> s_dash written ~2x (r7: WRITE 663 MB vs 360 ideal).
template<int USE_WS>
__global__ __launch_bounds__(NT, 2)
void gvp_main(const float* __restrict__ s, const float* __restrict__ V,
              const float* __restrict__ Wh, const float* __restrict__ Wmu,
              const float* __restrict__ Wmw, const float* __restrict__ Wmb,
              const float* __restrict__ Wgw, const float* __restrict__ Wgb,
              const unsigned short* __restrict__ wpack,
              float* __restrict__ out)
{
    // sX  bf16 [32][296] 18944 B: s cols 0-255 | s_h cols 256-287;
    //     after GEMM: sigmoid(s_m) cols 0-255, gate bf16 cols 256-287.
    // sWb 2 x 4096 shorts 16384 B: W half-chunk double buffer;
    //     then relu f32 restage [16][256] per pass; then f32 V_dash scratch.
    // sV  f32  [32][96]  12288 B: V tile, then V_h.
    __shared__ __attribute__((aligned(16))) unsigned short sX[BN * SXS];
    __shared__ __attribute__((aligned(16))) unsigned short sWb[2 * 4096];
    __shared__ __attribute__((aligned(16))) float sV[BN * 96];

    const int t  = threadIdx.x;
    const int w  = t >> 6, l = t & 63;
    const int fr = l & 15, fq = l >> 4;
    const int n0 = blockIdx.x * BN;

    // ---------------- stage s -> sX (bf16), V -> sV ----------------
    #pragma unroll
    for (int i = 0; i < 8; ++i) {
        int n = i * 4 + w;
        float4 x4 = *(const float4*)&s[(size_t)(n0 + n) * 256 + 4 * l];
        ushort4 h4; h4.x = f2b(x4.x); h4.y = f2b(x4.y); h4.z = f2b(x4.z); h4.w = f2b(x4.w);
        *(ushort4*)&sX[n * SXS + 4 * l] = h4;
    }
    #pragma unroll
    for (int i = 0; i < 3; ++i) {
        int f = i * NT + t;
        *(float4*)&sV[f * 4] = *(const float4*)&V[(size_t)n0 * 96 + f * 4];
    }
    // prologue: stage W half-chunk 0 into buf0 (wave-linear slice, async)
    if (USE_WS) {
        const unsigned short* src = wpack + w * 1024 + l * 8;
        unsigned short* dst = sWb + w * 1024;
        glds16(src, dst);
        glds16(src + 512, dst + 512);
    } else {
        int og = t >> 1, kh = t & 1;                 // ch=0, ks=0
        const float* p = &Wmw[og * 288 + kh * 16];
        *(bf16x8*)&sWb[og * 32 + kh * 16 + 0] = cvt8(p);
        *(bf16x8*)&sWb[og * 32 + kh * 16 + 8] = cvt8(p + 8);
    }
    __syncthreads();   // drains vmcnt -> chunk 0 resident; staging visible

    // ---------------- phase A: V_h = Wh@V (f32, Wh from L1), s_h -> sX[.,256..] --
    float vh[4][3];
    #pragma unroll
    for (int i = 0; i < 4; ++i) {
        int p = i * NT + t;
        int n = p >> 5, h = p & 31;
        const float4* vt4 = (const float4*)&sV[n * 96];
        const float4* wh4 = (const float4*)&Wh[h * 32];
        float a0 = 0.f, a1 = 0.f, a2 = 0.f;
        #pragma unroll
        for (int v4 = 0; v4 < 8; ++v4) {
            float4 wv = wh4[v4];
            float4 p0 = vt4[v4 * 3 + 0], p1 = vt4[v4 * 3 + 1], p2 = vt4[v4 * 3 + 2];
            a0 = fmaf(wv.x, p0.x, a0); a1 = fmaf(wv.x, p0.y, a1); a2 = fmaf(wv.x, p0.z, a2);
            a0 = fmaf(wv.y, p0.w, a0); a1 = fmaf(wv.y, p1.x, a1); a2 = fmaf(wv.y, p1.y, a2);
            a0 = fmaf(wv.z, p1.z, a0); a1 = fmaf(wv.z, p1.w, a1); a2 = fmaf(wv.z, p2.x, a2);
            a0 = fmaf(wv.w, p2.y, a0); a1 = fmaf(wv.w, p2.z, a1); a2 = fmaf(wv.w, p2.w, a2);
        }
        vh[i][0] = a0; vh[i][1] = a1; vh[i][2] = a2;
        float nrm = sqrtf(fmaf(a0, a0, fmaf(a1, a1, a2 * a2)));
        sX[n * SXS + 256 + h] = f2b(fmaxf(nrm, 1e-4f));
    }
    __syncthreads();            // V-tile reads done; s_h visible
    #pragma unroll
    for (int i = 0; i < 4; ++i) {
        int p = i * NT + t;
        int n = p >> 5, h = p & 31;
        sV[n * 96 + h * 3 + 0] = vh[i][0];
        sV[n * 96 + h * 3 + 1] = vh[i][1];
        sV[n * 96 + h * 3 + 2] = vh[i][2];
    }

    // ---------------- main GEMM: 18 half-chunk iters, dbuf glds, 1 barrier/iter --
    // acc[mt][ji]: ji = ch*2 + jt -> col = ch*128 + w*32 + jt*16 + fr
    f32x4 acc[2][4];
    #pragma unroll
    for (int mt = 0; mt < 2; ++mt)
        #pragma unroll
        for (int j = 0; j < 4; ++j) acc[mt][j] = (f32x4){0.f, 0.f, 0.f, 0.f};

    #pragma unroll
    for (int it = 0; it < 18; ++it) {
        if (it < 17) {          // stage next half-chunk into the other buffer
            if (USE_WS) {
                const unsigned short* src = wpack + (it + 1) * 4096 + w * 1024 + l * 8;
                unsigned short* dst = sWb + ((it + 1) & 1) * 4096 + w * 1024;
                glds16(src, dst);
                glds16(src + 512, dst + 512);
            } else {
                int ks1 = (it + 1) >> 1, ch1 = (it + 1) & 1;
                int og = ch1 * 128 + (t >> 1), kh = t & 1;
                const float* p = &Wmw[og * 288 + ks1 * 32 + kh * 16];
                *(bf16x8*)&sWb[((it + 1) & 1) * 4096 + (t >> 1) * 32 + kh * 16 + 0] = cvt8(p);
                *(bf16x8*)&sWb[((it + 1) & 1) * 4096 + (t >> 1) * 32 + kh * 16 + 8] = cvt8(p + 8);
            }
        }
        const int ks = it >> 1;
        const unsigned short* bw = sWb + (it & 1) * 4096;
        bf16x8 a0 = *(const bf16x8*)&sX[fr * SXS + ks * 32 + fq * 8];
        bf16x8 a1 = *(const bf16x8*)&sX[(16 + fr) * SXS + ks * 32 + fq * 8];
        bf16x8 b0 = *(const bf16x8*)&bw[(w * 32 + fr) * 32 + fq * 8];
        bf16x8 b1 = *(const bf16x8*)&bw[(w * 32 + 16 + fr) * 32 + fq * 8];
        const int ji = (it & 1) * 2;   // static under full unroll
        acc[0][ji + 0] = __builtin_amdgcn_mfma_f32_16x16x32_bf16(a0, b0, acc[0][ji + 0], 0, 0, 0);
        acc[1][ji + 0] = __builtin_amdgcn_mfma_f32_16x16x32_bf16(a1, b0, acc[1][ji + 0], 0, 0, 0);
        acc[0][ji + 1] = __builtin_amdgcn_mfma_f32_16x16x32_bf16(a0, b1, acc[0][ji + 1], 0, 0, 0);
        acc[1][ji + 1] = __builtin_amdgcn_mfma_f32_16x16x32_bf16(a1, b1, acc[1][ji + 1], 0, 0, 0);
        __syncthreads();        // buffer swap; drains glds for it+1
    }

    // ---------------- epilogue: sigmoid -> sX; relu restaged via sWb, f4 stores --
    float bias[4];
    #pragma unroll
    for (int ji = 0; ji < 4; ++ji)
        bias[ji] = Wmb[(ji >> 1) * 128 + w * 32 + (ji & 1) * 16 + fr];

    float* sRel = (float*)sWb;  // [16][256] f32 = 16384 B per pass (sWb exactly)
    #pragma unroll
    for (int mt = 0; mt < 2; ++mt) {
        #pragma unroll
        for (int r = 0; r < 4; ++r) {
            int row  = fq * 4 + r;            // 0..15 within pass
            int node = mt * 16 + row;
            #pragma unroll
            for (int ji = 0; ji < 4; ++ji) {
                int col = (ji >> 1) * 128 + w * 32 + (ji & 1) * 16 + fr;
                float m = acc[mt][ji][r] + bias[ji];
                sX[node * SXS + col] = f2b(1.f / (1.f + __expf(-m)));
                sRel[row * 256 + col] = fmaxf(m, 0.f);
            }
        }
        __syncthreads();
        #pragma unroll
        for (int i = 0; i < 4; ++i) {
            int flat = i * NT + t;            // 1024 f4 slots = 16 rows x 64
            int row = flat >> 6, c4 = flat & 63;
            float4 v4 = *(const float4*)&sRel[row * 256 + c4 * 4];
            *(float4*)&out[(size_t)(n0 + mt * 16 + row) * 256 + c4 * 4] = v4;
        }
        __syncthreads();        // sRel reusable / all sigmoid visible after mt=1
    }

    // ---------------- gate GEMM (B direct from global); gate bf16 -> sX[.,256..] -
    {
        const int gmt = w & 1, gnt = w >> 1;
        f32x4 g = (f32x4){0.f, 0.f, 0.f, 0.f};
        #pragma unroll
        for (int ks = 0; ks < 8; ++ks) {
            bf16x8 a = *(const bf16x8*)&sX[(gmt * 16 + fr) * SXS + ks * 32 + fq * 8];
            bf16x8 b;
            if (USE_WS) b = *(const bf16x8*)&wpack[73728 + ks * 1024 + (gnt * 16 + fr) * 32 + fq * 8];
            else        b = cvt8(&Wgw[(gnt * 16 + fr) * 256 + ks * 32 + fq * 8]);
            g = __builtin_amdgcn_mfma_f32_16x16x32_bf16(a, b, g, 0, 0, 0);
        }
        int mo = gnt * 16 + fr;
        float gb = Wgb[mo];
        #pragma unroll
        for (int r = 0; r < 4; ++r) {
            int node = gmt * 16 + fq * 4 + r;
            sX[node * SXS + 256 + mo] = f2b(1.f / (1.f + __expf(-(g[r] + gb))));
        }
    }
    __syncthreads();            // gate visible; sWb dead -> f32 V_dash scratch

    // ---------------- phase D: V_mu = Wmu@V_h (f32); gate; coalesced store ------
    float* sc = (float*)sWb;    // [32][96] f32 = 12288 B <= 16384 B
    #pragma unroll
    for (int i = 0; i < 4; ++i) {
        int p = i * NT + t;
        int n = p >> 5, m = p & 31;
        const float4* vt4 = (const float4*)&sV[n * 96];
        const float4* wm4 = (const float4*)&Wmu[m * 32];
        float a0 = 0.f, a1 = 0.f, a2 = 0.f;
        #pragma unroll
        for (int v4 = 0; v4 < 8; ++v4) {
            float4 wv = wm4[v4];
            float4 p0 = vt4[v4 * 3 + 0], p1 = vt4[v4 * 3 + 1], p2 = vt4[v4 * 3 + 2];
            a0 = fmaf(wv.x, p0.x, a0); a1 = fmaf(wv.x, p0.y, a1); a2 = fmaf(wv.x, p0.z, a2);
            a0 = fmaf(wv.y, p0.w, a0); a1 = fmaf(wv.y, p1.x, a1); a2 = fmaf(wv.y, p1.y, a2);
            a0 = fmaf(wv.z, p1.z, a0); a1 = fmaf(wv.z, p1.w, a1); a2 = fmaf(wv.z, p2.x, a2);
            a0 = fmaf(wv.w, p2.y, a0); a1 = fmaf(wv.w, p2.z, a1); a2 = fmaf(wv.w, p2.w, a2);
        }
        float g = b2f(sX[n * SXS + 256 + m]);
        sc[n * 96 + m * 3 + 0] = g * a0;
        sc[n * 96 + m * 3 + 1] = g * a1;
        sc[n * 96 + m * 3 + 2] = g * a2;
    }
    __syncthreads();
    const size_t VBASE = (size_t)NTOT * 256;
    #pragma unroll
    for (int i = 0; i < 3; ++i) {
        int f = i * NT + t;
        *(float4*)&out[VBASE + (size_t)n0 * 96 + f * 4] = *(const float4*)&sc[f * 4];
    }
}

extern "C" void kernel_launch(void* const* d_in, const int* in_sizes, int n_in,
                              void* d_out, int out_size, void* d_ws, size_t ws_size,
                              hipStream_t stream) {
    const float* s   = (const float*)d_in[0];
    const float* V   = (const float*)d_in[1];
    const float* Wh  = (const float*)d_in[2];
    const float* Wmu = (const float*)d_in[3];
    const float* Wmw = (const float*)d_in[4];
    const float* Wmb = (const float*)d_in[5];
    const float* Wgw = (const float*)d_in[6];
    const float* Wgb = (const float*)d_in[7];
    float* out = (float*)d_out;

    dim3 grid(NTOT / BN);   // 8192
    dim3 block(NT);         // 256

    if (ws_size >= 163840) {
        pack_w<<<320, 256, 0, stream>>>(Wmw, Wgw, (unsigned short*)d_ws);
        gvp_main<1><<<grid, block, 0, stream>>>(s, V, Wh, Wmu, Wmw, Wmb, Wgw, Wgb,
                                                (const unsigned short*)d_ws, out);
    } else {
        gvp_main<0><<<grid, block, 0, stream>>>(s, V, Wh, Wmu, Wmw, Wmb, Wgw, Wgb,
                                                nullptr, out);
    }
}